// Round 1
// baseline (1122.605 us; speedup 1.0000x reference)
//
#include <hip/hip_runtime.h>
#include <hip/hip_bf16.h>
#include <stdint.h>

// ---------------------------------------------------------------------------
// LinearSelfAttention (Performer-style) on gfx950.
//   V     = x @ W_v                     (f16 MFMA, A cast f32->f16 in-staging)
//   P|S   = pos/slopes @ W_pf           (split-f16 virtual K=3072 [hi|hi|lo])
//           FUSED into one dispatch: gridDim.z=2 selects pos(z=0)/slopes(z=1).
//           z=0 stores scale*acc -> Pb; z=1 stores offs*scale*acc -> Sb plus
//           slope norms. The kp = P + offs*scale*S combine moved into the
//           fourier A-staging (AMODE=3), killing the P->S serialization.
//   q',k' = MFMA GEMM vs proj (split-f16 K=192), sin/cos epilogue, q+k merged
//   kvT   = sum_l v[l][d] k'[l][m]      (f16 MFMA, LDS transpose, split-K=16)
//   z     = q'' @ kvT                   (batched f16 MFMA)
//   out   = z @ W_o                     (f16 MFMA, f32 out)
// R4 post-mortem basis: P/S GEMMs were 50% of runtime at MfmaUtil 14.5%,
// Occupancy 22% (512-block grids = 2 blocks/CU = 2 waves/SIMD; latency-bound,
// not BW: HBM 11%). Fusion doubles the grid to 1024 blocks (4/CU resident,
// LDS-capped at 5). Workspace unchanged: 218.6 MB.
// ---------------------------------------------------------------------------

typedef _Float16 hx8 __attribute__((ext_vector_type(8)));
typedef _Float16 hx4 __attribute__((ext_vector_type(4)));
typedef float    fx4 __attribute__((ext_vector_type(4)));

#define H_   16
#define D_   64
#define L_   4096
#define B_   4
#define BL_  16384
#define KV_SPLIT 16

// ---------------- prep kernels ----------------
// W [1024][1024] f32 -> WT [1024][1024] f16 (WT[n][k] = W[k][n])
__global__ __launch_bounds__(256) void wt_k(const float* __restrict__ W,
                                            _Float16* __restrict__ WT) {
  __shared__ float tile[64][65];
  int t = threadIdx.x; int c = t & 63; int r0 = t >> 6;
  int bx = blockIdx.x * 64, by = blockIdx.y * 64;
  for (int r = r0; r < 64; r += 4) tile[r][c] = W[(long)(by + r) * 1024 + bx + c];
  __syncthreads();
  for (int r = r0; r < 64; r += 4)
    WT[(long)(bx + r) * 1024 + by + c] = (_Float16)tile[c][r];
}

// W_pf -> WT3 [1024][3072] f16 sections: [hi ; hi ; lo] (transposed)
__global__ __launch_bounds__(256) void wpf3_k(const float* __restrict__ W,
                                              _Float16* __restrict__ WT3) {
  __shared__ float tile[64][65];
  int t = threadIdx.x; int c = t & 63; int r0 = t >> 6;
  int bx = blockIdx.x * 64, by = blockIdx.y * 64;
  for (int r = r0; r < 64; r += 4) tile[r][c] = W[(long)(by + r) * 1024 + bx + c];
  __syncthreads();
  for (int r = r0; r < 64; r += 4) {
    float x = tile[c][r];
    _Float16 hi = (_Float16)x;
    _Float16 lo = (_Float16)(x - (float)hi);
    long base = (long)(bx + r) * 3072 + by + c;
    WT3[base] = hi; WT3[base + 1024] = hi; WT3[base + 2048] = lo;
  }
}

// proj [128][64] f32 -> proj3T [128][192] f16 [hi | hi | lo], cnorm folded.
__global__ __launch_bounds__(256) void proj3_k(const float* __restrict__ proj,
                                               _Float16* __restrict__ proj3T) {
  int i = blockIdx.x * 256 + threadIdx.x;
  if (i >= 8192) return;
  int m = i >> 6, d = i & 63;
  float p = 0.35355339059327373f * proj[i];    // 1/64^0.25 folded
  _Float16 hi = (_Float16)p;
  _Float16 lo = (_Float16)(p - (float)hi);
  proj3T[(long)m * 192 + d]       = hi;
  proj3T[(long)m * 192 + 64 + d]  = hi;
  proj3T[(long)m * 192 + 128 + d] = lo;
}

__global__ __launch_bounds__(256) void zero_k(float* __restrict__ p, int n4) {
  int i = blockIdx.x * 256 + threadIdx.x;
  int stride = gridDim.x * 256;
  fx4 z = {0.f, 0.f, 0.f, 0.f};
  for (; i < n4; i += stride) ((fx4*)p)[i] = z;
}

__global__ __launch_bounds__(256) void cast_out_f16_k(const float* __restrict__ in,
                                                      _Float16* __restrict__ out, int n) {
  int i = blockIdx.x * 256 + threadIdx.x;
  int stride = gridDim.x * 256;
  for (; i < n; i += stride) out[i] = (_Float16)in[i];
}

// ---------------- generic f16 MFMA GEMM:  C[M][N] = A[M][K] @ BT[N][K]^T ----
// BK=64, 256 threads, 4 waves 2x2; XOR-swizzled LDS (conflict-free b128).
// GRID: blockIdx.x = M-tile (by), blockIdx.y = N-tile (bx) — XCD-aware: blocks
// sharing A rows differ by gridDim.x in linear id => same id%8 => same XCD L2.
// AMODE: 0 = A f16; 1 = A f32 (cast in staging); 2 = A f32, virtual-K split
//        [hi|lo|hi] in sections of (1<<SECSH) (SECSH=10: K=3072; 6: K=192);
//        3 = like 2, but when (bz&15) the staged value is A32[i] + A32[i+sAb]
//        (kp combine: P + precombined offs*scale*S, both f32).
// EPI: 0 plain store | 1 fourier sin/cos (norms if (bz&15)==0) |
//      2 C = scp[h]*acc | 3 C = Pprev + ofp[h]*scp[h]*acc, nout=||acc_row||/L |
//      4 fused P|S: bz==0 -> C = scp[h]*acc; bz==1 -> A comes from Pprev,
//        C(+sCh auto) = ofp[h]*scp[h]*acc, nout = ||acc_row||/L.
template<int BM, int BN, int AMODE, int SECSH, int EPI, typename OUT_T>
__global__ __launch_bounds__(256) void gemm_bt_k(
    const void* __restrict__ Av, const _Float16* __restrict__ BT,
    OUT_T* __restrict__ C, int K, int lda, int ldb, int ldc,
    long sAb, long sAh, long sBb, long sBh, long sCb, long sCh,
    const float* __restrict__ norms, const float* __restrict__ scp,
    const float* __restrict__ ofp, const float* __restrict__ Pprev,
    float* __restrict__ nout)
{
  __shared__ __align__(16) _Float16 sA[BM * 64];
  __shared__ __align__(16) _Float16 sB[BN * 64];
  const int t = threadIdx.x;
  const int lane = t & 63;
  const int w = t >> 6;
  const int wm = w >> 1, wn = w & 1;
  const int by = blockIdx.x, bx = blockIdx.y, bz = blockIdx.z;
  long aoff = (long)(bz >> 4) * sAb + (long)(bz & 15) * sAh;
  BT += (long)(bz >> 4) * sBb + (long)(bz & 15) * sBh;
  C  += (long)(bz >> 4) * sCb + (long)(bz & 15) * sCh;
  const _Float16* A16 = (const _Float16*)Av + aoff;
  const float*    A32 = (const float*)Av + aoff;
  if constexpr (EPI == 4) {               // fused P|S: z=1 reads slopes
    if (bz & 15) A32 = Pprev + aoff;
  }
  constexpr int WTM = BM / 32, WTN = BN / 32;
  fx4 acc[WTM][WTN];
#pragma unroll
  for (int i = 0; i < WTM; ++i)
#pragma unroll
    for (int j = 0; j < WTN; ++j) acc[i][j] = (fx4){0.f, 0.f, 0.f, 0.f};

  for (int k0 = 0; k0 < K; k0 += 64) {
    __syncthreads();
    // ---- stage A tile [BM x 64] ----
    if constexpr (AMODE == 0) {
#pragma unroll
      for (int i = 0; i < BM / 32; ++i) {
        int s = i * 256 + t; int row = s >> 3; int kc = (s & 7) ^ (row & 7);
        *(uint4*)&sA[s * 8] =
            *(const uint4*)&A16[(long)(by * BM + row) * lda + k0 + kc * 8];
      }
    } else {
      int mode, cs;
      if constexpr (AMODE >= 2) { mode = k0 >> SECSH; cs = k0 & ((1 << SECSH) - 1); }
      else                      { mode = 0;           cs = k0;                      }
#pragma unroll
      for (int i = 0; i < BM / 32; ++i) {
        int s = i * 256 + t; int row = s >> 3; int kc = (s & 7) ^ (row & 7);
        const float* src = A32 + (long)(by * BM + row) * lda + cs + kc * 8;
        fx4 v0 = *(const fx4*)src;
        fx4 v1 = *(const fx4*)(src + 4);
        if constexpr (AMODE == 3) {
          if (bz & 15) {                  // k'-pass: kp = P + (offs*scale*S)
            const float* src2 = src + sAb;
            fx4 w0 = *(const fx4*)src2;
            fx4 w1 = *(const fx4*)(src2 + 4);
#pragma unroll
            for (int e = 0; e < 4; ++e) { v0[e] += w0[e]; v1[e] += w1[e]; }
          }
        }
        hx8 hv;
        if (mode != 1) {
#pragma unroll
          for (int e = 0; e < 4; ++e) { hv[e] = (_Float16)v0[e]; hv[4 + e] = (_Float16)v1[e]; }
        } else {
#pragma unroll
          for (int e = 0; e < 4; ++e) {
            _Float16 h0 = (_Float16)v0[e]; hv[e]     = (_Float16)(v0[e] - (float)h0);
            _Float16 h1 = (_Float16)v1[e]; hv[4 + e] = (_Float16)(v1[e] - (float)h1);
          }
        }
        *(hx8*)&sA[s * 8] = hv;
      }
    }
    // ---- stage B tile [BN x 64] ----
#pragma unroll
    for (int i = 0; i < BN / 32; ++i) {
      int s = i * 256 + t; int row = s >> 3; int kc = (s & 7) ^ (row & 7);
      *(uint4*)&sB[s * 8] =
          *(const uint4*)&BT[(long)(bx * BN + row) * ldb + k0 + kc * 8];
    }
    __syncthreads();
#pragma unroll
    for (int kk = 0; kk < 64; kk += 32) {
      hx8 af[WTM], bf[WTN];
      int kcb = (kk >> 3) + (lane >> 4);
#pragma unroll
      for (int i = 0; i < WTM; ++i) {
        int r = wm * (BM / 2) + i * 16 + (lane & 15);
        af[i] = *(const hx8*)&sA[(r * 8 + (kcb ^ (r & 7))) * 8];
      }
#pragma unroll
      for (int j = 0; j < WTN; ++j) {
        int r = wn * (BN / 2) + j * 16 + (lane & 15);
        bf[j] = *(const hx8*)&sB[(r * 8 + (kcb ^ (r & 7))) * 8];
      }
#pragma unroll
      for (int i = 0; i < WTM; ++i)
#pragma unroll
        for (int j = 0; j < WTN; ++j)
          acc[i][j] = __builtin_amdgcn_mfma_f32_16x16x32_f16(af[i], bf[j], acc[i][j], 0, 0, 0);
    }
  }
  if constexpr (EPI == 0) {
#pragma unroll
    for (int i = 0; i < WTM; ++i) {
#pragma unroll
      for (int j = 0; j < WTN; ++j) {
        int rowb = by * BM + wm * (BM / 2) + i * 16 + ((lane >> 4) << 2);
        int col  = bx * BN + wn * (BN / 2) + j * 16 + (lane & 15);
#pragma unroll
        for (int r = 0; r < 4; ++r)
          C[(long)(rowb + r) * ldc + col] = (OUT_T)acc[i][j][r];
      }
    }
  } else if constexpr (EPI == 1) {
    const float inv2pi = 0.15915494309189535f;
    const float ratio  = 0.08838834764831845f;   // 1/sqrt(128)
    const bool useN = ((bz & 15) == 0);
#pragma unroll
    for (int i = 0; i < WTM; ++i) {
#pragma unroll
      for (int j = 0; j < WTN; ++j) {
        int rowb = by * BM + wm * (BM / 2) + i * 16 + ((lane >> 4) << 2);
        int col  = bx * BN + wn * (BN / 2) + j * 16 + (lane & 15);
#pragma unroll
        for (int r = 0; r < 4; ++r) {
          int row = rowb + r;                     // row = l*16 + h
          float rn = ratio * (useN ? norms[row] : 1.0f);
          long ob = ((long)(row & 15) * 4096 + (row >> 4)) * 256;
          float v = acc[i][j][r] * inv2pi;
          v -= floorf(v);                         // revolutions in [0,1)
          C[ob + col]       = (OUT_T)(rn * __builtin_amdgcn_sinf(v));
          C[ob + 128 + col] = (OUT_T)(rn * __builtin_amdgcn_cosf(v));
        }
      }
    }
  } else if constexpr (EPI == 2) {
    const int h = ((bx * BN) >> 6) + wn;          // BN=128: 2 heads/block
    const float sc = scp[h];
#pragma unroll
    for (int i = 0; i < WTM; ++i) {
#pragma unroll
      for (int j = 0; j < WTN; ++j) {
        int rowb = by * BM + wm * (BM / 2) + i * 16 + ((lane >> 4) << 2);
        int col  = bx * BN + wn * (BN / 2) + j * 16 + (lane & 15);
#pragma unroll
        for (int r = 0; r < 4; ++r)
          C[(long)(rowb + r) * ldc + col] = (OUT_T)(sc * acc[i][j][r]);
      }
    }
  } else if constexpr (EPI == 3) {
    const int h = ((bx * BN) >> 6) + wn;
    const float sc = scp[h], of = ofp[h];
#pragma unroll
    for (int i = 0; i < WTM; ++i) {
      float sq[4] = {0.f, 0.f, 0.f, 0.f};
      int rowb = by * BM + wm * (BM / 2) + i * 16 + ((lane >> 4) << 2);
#pragma unroll
      for (int j = 0; j < WTN; ++j) {
        int col = bx * BN + wn * (BN / 2) + j * 16 + (lane & 15);
#pragma unroll
        for (int r = 0; r < 4; ++r) {
          float a = acc[i][j][r];
          sq[r] += a * a;
          C[(long)(rowb + r) * ldc + col] =
              (OUT_T)(Pprev[(long)(rowb + r) * ldc + col] + of * sc * a);
        }
      }
#pragma unroll
      for (int r = 0; r < 4; ++r) {               // 64-col norm: 4 j's x 16 lanes
        float s = sq[r];
        s += __shfl_xor(s, 1); s += __shfl_xor(s, 2);
        s += __shfl_xor(s, 4); s += __shfl_xor(s, 8);
        if ((lane & 15) == 0)
          nout[(long)(rowb + r) * 16 + h] = sqrtf(s) * (1.0f / 4096.0f);
      }
    }
  } else {                                        // EPI == 4: fused P|S
    const int h = ((bx * BN) >> 6) + wn;
    const float sc = scp[h];
    if ((bz & 15) == 0) {                         // P: C = scale*acc
#pragma unroll
      for (int i = 0; i < WTM; ++i) {
#pragma unroll
        for (int j = 0; j < WTN; ++j) {
          int rowb = by * BM + wm * (BM / 2) + i * 16 + ((lane >> 4) << 2);
          int col  = bx * BN + wn * (BN / 2) + j * 16 + (lane & 15);
#pragma unroll
          for (int r = 0; r < 4; ++r)
            C[(long)(rowb + r) * ldc + col] = (OUT_T)(sc * acc[i][j][r]);
        }
      }
    } else {                                      // S: C = offs*scale*acc, norms
      const float osc = ofp[h] * sc;
#pragma unroll
      for (int i = 0; i < WTM; ++i) {
        float sq[4] = {0.f, 0.f, 0.f, 0.f};
        int rowb = by * BM + wm * (BM / 2) + i * 16 + ((lane >> 4) << 2);
#pragma unroll
        for (int j = 0; j < WTN; ++j) {
          int col = bx * BN + wn * (BN / 2) + j * 16 + (lane & 15);
#pragma unroll
          for (int r = 0; r < 4; ++r) {
            float a = acc[i][j][r];
            sq[r] += a * a;
            C[(long)(rowb + r) * ldc + col] = (OUT_T)(osc * a);
          }
        }
#pragma unroll
        for (int r = 0; r < 4; ++r) {             // 64-col norm: 4 j's x 16 lanes
          float s = sq[r];
          s += __shfl_xor(s, 1); s += __shfl_xor(s, 2);
          s += __shfl_xor(s, 4); s += __shfl_xor(s, 8);
          if ((lane & 15) == 0)
            nout[(long)(rowb + r) * 16 + h] = sqrtf(s) * (1.0f / 4096.0f);
        }
      }
    }
  }
}

// ---------------- kv kernel (per-b): kvT[d][m] = sum_l v[l][d] * k'[l][m] ---
__global__ __launch_bounds__(256) void kv_k(const _Float16* __restrict__ Kp,
                                            const _Float16* __restrict__ Vhb,
                                            float* __restrict__ kvacc)
{
  __shared__ __align__(16) _Float16 sK[256 * 72];   // [m][l] stride 72
  __shared__ __align__(16) _Float16 sV[64 * 72];    // [d][l]
  const int t = threadIdx.x, lane = t & 63, w = t >> 6;
  const int h = blockIdx.x;
  const int l0 = blockIdx.y * (L_ / KV_SPLIT);
  fx4 acc[4][4];
#pragma unroll
  for (int i = 0; i < 4; ++i)
#pragma unroll
    for (int j = 0; j < 4; ++j) acc[i][j] = (fx4){0.f, 0.f, 0.f, 0.f};
  const _Float16* Kbase = Kp + (long)h * L_ * 256;
  for (int kt = 0; kt < L_ / KV_SPLIT; kt += 64) {
    __syncthreads();
#pragma unroll
    for (int i = 0; i < 8; ++i) {               // k' tile: 64 l x 256 m, transpose
      int mc = w + 4 * i;                       // 0..31 (wave-uniform)
      hx8 vv = *(const hx8*)&Kbase[(long)(l0 + kt + lane) * 256 + mc * 8];
#pragma unroll
      for (int e = 0; e < 8; ++e) sK[(mc * 8 + e) * 72 + lane] = vv[e];
    }
#pragma unroll
    for (int i = 0; i < 2; ++i) {               // v tile: 64 l x 64 d, transpose
      int dc = w + 4 * i;                       // 0..7
      hx8 vv = *(const hx8*)&Vhb[(long)(l0 + kt + lane) * 1024 + h * 64 + dc * 8];
#pragma unroll
      for (int e = 0; e < 8; ++e) sV[(dc * 8 + e) * 72 + lane] = vv[e];
    }
    __syncthreads();
#pragma unroll
    for (int kk = 0; kk < 64; kk += 32) {
      hx8 af[4], bf[4];
      int lfr = kk + ((lane >> 4) << 3);
#pragma unroll
      for (int i = 0; i < 4; ++i)
        af[i] = *(const hx8*)&sV[(i * 16 + (lane & 15)) * 72 + lfr];
#pragma unroll
      for (int j = 0; j < 4; ++j)
        bf[j] = *(const hx8*)&sK[(w * 64 + j * 16 + (lane & 15)) * 72 + lfr];
#pragma unroll
      for (int i = 0; i < 4; ++i)
#pragma unroll
        for (int j = 0; j < 4; ++j)
          acc[i][j] = __builtin_amdgcn_mfma_f32_16x16x32_f16(af[i], bf[j], acc[i][j], 0, 0, 0);
    }
  }
  float* obase = kvacc + (long)h * (64 * 256);
#pragma unroll
  for (int i = 0; i < 4; ++i)
#pragma unroll
    for (int j = 0; j < 4; ++j) {
      int d0 = i * 16 + ((lane >> 4) << 2);
      int m  = w * 64 + j * 16 + (lane & 15);
#pragma unroll
      for (int r = 0; r < 4; ++r)
        atomicAdd(&obase[(long)(d0 + r) * 256 + m], acc[i][j][r]);
    }
}

// ---------------------------------------------------------------------------
extern "C" void kernel_launch(void* const* d_in, const int* in_sizes, int n_in,
                              void* d_out, int out_size, void* d_ws, size_t ws_size,
                              hipStream_t stream) {
  const float* x     = (const float*)d_in[0];
  const float* pos   = (const float*)d_in[1];
  const float* slp   = (const float*)d_in[2];
  const float* Wv    = (const float*)d_in[3];
  const float* Wo    = (const float*)d_in[4];
  const float* Wpf   = (const float*)d_in[5];
  const float* scale = (const float*)d_in[6];
  const float* offs  = (const float*)d_in[7];
  const float* proj  = (const float*)d_in[8];
  float* out = (float*)d_out;
  char* ws = (char*)d_ws;

  // Arena ~218.6 MB. NOTE: Sb must follow Pb contiguously (fourier kp combine
  // reads S at +8388608 floats), kpr must follow qpr contiguously (fourier sCh
  // stride).
  size_t o = 0;
  auto alloc = [&](size_t bytes) { char* p = ws + o; o += (bytes + 255) & ~(size_t)255; return p; };
  float*    Pb     = (float*)alloc(33554432);      // [2][4096][1024] f32 (= qp, scaled)
  float*    Sb     = (float*)alloc(33554432);      // (= offs*scale*slope_proj) == Pb + 8388608
  _Float16* qpr    = (_Float16*)alloc(33554432);   // per-b [H][L][256] f16
  _Float16* kpr    = (_Float16*)alloc(33554432);   //                 == qpr + 16777216
  _Float16* Vh     = (_Float16*)alloc(33554432);   // [BL][1024] f16
  _Float16* Zb     = (_Float16*)alloc(33554432);   // [BL][1024] f16
  _Float16* WvT    = (_Float16*)alloc(2097152);
  _Float16* WoT    = (_Float16*)alloc(2097152);
  _Float16* Wpf3T  = (_Float16*)alloc(6291456);    // [1024][3072] [hi;hi;lo]
  _Float16* proj3T = (_Float16*)alloc(49152);      // [128][192] [hi|hi|lo]
  float*    normsB = (float*)alloc(524288);        // [8192][16] f32 per super-batch
  float*    kvacc  = (float*)alloc(4194304);       // [BH][64][256] f32
  _Float16* kvh    = (_Float16*)alloc(2097152);
  (void)Sb; (void)ws_size; (void)in_sizes; (void)n_in; (void)out_size;

  // prep
  wt_k<<<dim3(16, 16), 256, 0, stream>>>(Wv, WvT);
  wt_k<<<dim3(16, 16), 256, 0, stream>>>(Wo, WoT);
  wpf3_k<<<dim3(16, 16), 256, 0, stream>>>(Wpf, Wpf3T);
  proj3_k<<<32, 256, 0, stream>>>(proj, proj3T);
  zero_k<<<256, 256, 0, stream>>>(kvacc, 262144);

  // V = x @ W_v (A: f32 cast in staging; f16 out), M=16384, grid (M,N)-swapped
  gemm_bt_k<128, 128, 1, 0, 0, _Float16><<<dim3(128, 8, 1), 256, 0, stream>>>(
      x, WvT, Vh, 1024, 1024, 1024, 1024, 0, 0, 0, 0, 0, 0,
      nullptr, nullptr, nullptr, nullptr, nullptr);

  for (int sb = 0; sb < 2; ++sb) {
    const float* pos_sb = pos + (long)sb * 8192 * 1024;
    const float* slp_sb = slp + (long)sb * 8192 * 1024;
    // Fused P|S: z=0 -> Pb = scale*(pos@W); z=1 -> Sb = offs*scale*(slp@W)
    // (+ slope norms). 1024 blocks = 4/CU. split-f16 K=3072, M=8192 (2 b's).
    gemm_bt_k<128, 128, 2, 10, 4, float><<<dim3(64, 8, 2), 256, 0, stream>>>(
        pos_sb, Wpf3T, Pb, 3072, 1024, 3072, 1024, 0, 0, 0, 0, 0, 8388608L,
        nullptr, scale, offs, slp_sb, normsB);

    for (int bb = 0; bb < 2; ++bb) {
      int b = sb * 2 + bb;
      _Float16* Vh_b  = Vh + (long)b * L_ * 1024;
      _Float16* Zb_b  = Zb + (long)b * L_ * 1024;
      float* kvacc_b  = kvacc + (long)b * H_ * 64 * 256;
      _Float16* kvh_b = kvh   + (long)b * H_ * 64 * 256;
      // fourier q (bz=0, A=Pb_b, norms) + k (bz=1, A=Pb_b + Sb_b combined in
      // staging via sAb=+8388608) in one launch; K=192 split-f16 vs proj3T;
      // M=65536 rows of [l*16+h][64]
      gemm_bt_k<128, 128, 3, 6, 1, _Float16><<<dim3(512, 1, 2), 256, 0, stream>>>(
          Pb + (long)bb * 4194304, proj3T, qpr, 192, 64, 192, 0,
          8388608L, 0L, 0, 0, 0, 16777216L,
          normsB + (long)bb * 65536, nullptr, nullptr, nullptr, nullptr);
      // kv (split-K=16 over L with atomics) -> kvacc_b; cast to f16
      kv_k<<<dim3(16, KV_SPLIT), 256, 0, stream>>>(kpr, Vh_b, kvacc_b);
      cast_out_f16_k<<<1024, 256, 0, stream>>>(kvacc_b, kvh_b, 262144);
      // z = q'' @ kvT (batched over h), C -> Zb_b [L][1024]
      gemm_bt_k<128, 64, 0, 0, 0, _Float16><<<dim3(32, 1, 16), 256, 0, stream>>>(
          qpr, kvh_b, Zb_b, 256, 256, 256, 1024,
          0L, (long)L_ * 256, 0L, 16384L, 0L, 64L,
          nullptr, nullptr, nullptr, nullptr, nullptr);
    }
  }
  // out = z @ W_o (f32 out), M=16384
  gemm_bt_k<128, 128, 0, 0, 0, float><<<dim3(128, 8, 1), 256, 0, stream>>>(
      Zb, WoT, out, 1024, 1024, 1024, 1024, 0, 0, 0, 0, 0, 0,
      nullptr, nullptr, nullptr, nullptr, nullptr);
}

// Round 2
// 943.284 us; speedup vs baseline: 1.1901x; 1.1901x over previous
//
#include <hip/hip_runtime.h>
#include <hip/hip_bf16.h>
#include <stdint.h>

// ---------------------------------------------------------------------------
// LinearSelfAttention (Performer-style) on gfx950.
//   pre:  pos/slp -> f16 [hi|lo] (per-sb, aliased onto qpr/kpr), x -> f16 (Zb)
//   V     = x16 @ W_v                   (f16 MFMA, global_load_lds staging)
//   P|S   = pos/slp @ W_pf              (pre-split f16, virtual K=3072, one
//           dispatch gridDim.z=2; P -> scale*acc, S -> offs*scale*acc + norms)
//   q',k' = MFMA GEMM vs proj (split-f16 K=192, A f32 kp-combine in staging),
//           sin/cos epilogue, q+k merged in one launch
//   kvT   = sum_l v[l][d] k'[l][m]      (f16 MFMA, LDS transpose, split-K=16)
//   z     = q'' @ kvT                   (batched f16 MFMA, gload_lds staging)
//   out   = z @ W_o                     (f16 MFMA, f32 out, gload_lds staging)
// R5 basis: fused P|S stayed at 15% MfmaUtil / 23% Occ — grid-size fusion was
// neutral => limiter is per-wave staging cost + VGPR residency, not TLP count.
// Fix: conversion hoisted out of the k-loop (was re-done 24x per A element),
// f16 staging via global_load_lds (linear LDS dest + pre-swizzled global src,
// read-side XOR unchanged). Workspace unchanged: 218.6 MB (aliased buffers).
// ---------------------------------------------------------------------------

typedef _Float16 hx8 __attribute__((ext_vector_type(8)));
typedef _Float16 hx4 __attribute__((ext_vector_type(4)));
typedef float    fx4 __attribute__((ext_vector_type(4)));

#define H_   16
#define D_   64
#define L_   4096
#define B_   4
#define KV_SPLIT 16

// global -> LDS direct (16B/lane). LDS dest must be wave-uniform; HW adds
// lane*16. Global src is per-lane (carries the XOR swizzle).
__device__ __forceinline__ void g2l16(const _Float16* g, _Float16* l) {
  __builtin_amdgcn_global_load_lds(
      (const __attribute__((address_space(1))) void*)g,
      (__attribute__((address_space(3))) void*)l, 16, 0, 0);
}

// ---------------- prep kernels ----------------
// W [1024][1024] f32 -> WT [1024][1024] f16 (WT[n][k] = W[k][n])
__global__ __launch_bounds__(256) void wt_k(const float* __restrict__ W,
                                            _Float16* __restrict__ WT) {
  __shared__ float tile[64][65];
  int t = threadIdx.x; int c = t & 63; int r0 = t >> 6;
  int bx = blockIdx.x * 64, by = blockIdx.y * 64;
  for (int r = r0; r < 64; r += 4) tile[r][c] = W[(long)(by + r) * 1024 + bx + c];
  __syncthreads();
  for (int r = r0; r < 64; r += 4)
    WT[(long)(bx + r) * 1024 + by + c] = (_Float16)tile[c][r];
}

// W_pf -> WT3 [1024][3072] f16 sections: [hi ; hi ; lo] (transposed)
__global__ __launch_bounds__(256) void wpf3_k(const float* __restrict__ W,
                                              _Float16* __restrict__ WT3) {
  __shared__ float tile[64][65];
  int t = threadIdx.x; int c = t & 63; int r0 = t >> 6;
  int bx = blockIdx.x * 64, by = blockIdx.y * 64;
  for (int r = r0; r < 64; r += 4) tile[r][c] = W[(long)(by + r) * 1024 + bx + c];
  __syncthreads();
  for (int r = r0; r < 64; r += 4) {
    float x = tile[c][r];
    _Float16 hi = (_Float16)x;
    _Float16 lo = (_Float16)(x - (float)hi);
    long base = (long)(bx + r) * 3072 + by + c;
    WT3[base] = hi; WT3[base + 1024] = hi; WT3[base + 2048] = lo;
  }
}

// proj [128][64] f32 -> proj3T [128][192] f16 [hi | hi | lo], cnorm folded.
__global__ __launch_bounds__(256) void proj3_k(const float* __restrict__ proj,
                                               _Float16* __restrict__ proj3T) {
  int i = blockIdx.x * 256 + threadIdx.x;
  if (i >= 8192) return;
  int m = i >> 6, d = i & 63;
  float p = 0.35355339059327373f * proj[i];    // 1/64^0.25 folded
  _Float16 hi = (_Float16)p;
  _Float16 lo = (_Float16)(p - (float)hi);
  proj3T[(long)m * 192 + d]       = hi;
  proj3T[(long)m * 192 + 64 + d]  = hi;
  proj3T[(long)m * 192 + 128 + d] = lo;
}

__global__ __launch_bounds__(256) void zero_k(float* __restrict__ p, int n4) {
  int i = blockIdx.x * 256 + threadIdx.x;
  int stride = gridDim.x * 256;
  fx4 z = {0.f, 0.f, 0.f, 0.f};
  for (; i < n4; i += stride) ((fx4*)p)[i] = z;
}

__global__ __launch_bounds__(256) void cast_out_f16_k(const float* __restrict__ in,
                                                      _Float16* __restrict__ out, int n) {
  int i = blockIdx.x * 256 + threadIdx.x;
  int stride = gridDim.x * 256;
  for (; i < n; i += stride) out[i] = (_Float16)in[i];
}

// [8192][1024] f32 -> [8192][2048] f16 [hi|lo]. Exactly 4096 blocks x 256 thr.
__global__ __launch_bounds__(256) void cvt_hilo_k(const float* __restrict__ in,
                                                  _Float16* __restrict__ out) {
  long i = (long)blockIdx.x * 256 + threadIdx.x;   // 1M threads, 8 elems each
  long idx = i * 8;
  int row = (int)(idx >> 10), c = (int)(idx & 1023);
  fx4 a = *(const fx4*)&in[idx];
  fx4 b = *(const fx4*)&in[idx + 4];
  hx8 hi, lo;
#pragma unroll
  for (int e = 0; e < 4; ++e) {
    _Float16 h0 = (_Float16)a[e]; hi[e] = h0;     lo[e]     = (_Float16)(a[e] - (float)h0);
    _Float16 h1 = (_Float16)b[e]; hi[4 + e] = h1; lo[4 + e] = (_Float16)(b[e] - (float)h1);
  }
  *(hx8*)&out[(long)row * 2048 + c]        = hi;
  *(hx8*)&out[(long)row * 2048 + 1024 + c] = lo;
}

// plain f32 -> f16 cast, 8/thread vectorized
__global__ __launch_bounds__(256) void cvt16_k(const float* __restrict__ in,
                                               _Float16* __restrict__ out, long n8) {
  long i = (long)blockIdx.x * 256 + threadIdx.x;
  if (i >= n8) return;
  long idx = i * 8;
  fx4 a = *(const fx4*)&in[idx];
  fx4 b = *(const fx4*)&in[idx + 4];
  hx8 h;
#pragma unroll
  for (int e = 0; e < 4; ++e) { h[e] = (_Float16)a[e]; h[4 + e] = (_Float16)b[e]; }
  *(hx8*)&out[idx] = h;
}

// ---------------- generic f16 MFMA GEMM:  C[M][N] = A[M][K] @ BT[N][K]^T ----
// BK=64, 256 threads, 4 waves 2x2; XOR-swizzled LDS (conflict-free b128).
// AMODE: 0 = A f16, global_load_lds staging (pre-swizzled global src);
//        1 = A f32 (cast in staging, reg path); 2 = A f32 virtual-K split
//        [hi|lo|hi] sections of (1<<SECSH); 3 = like 2 + kp combine when bz&15;
//        4 = A f16 pre-split [hi|lo] (lda=2*(1<<SECSH)), gload_lds staging,
//            section map k0 -> {hi, lo, hi}.
// EPI: 0 plain | 1 fourier sin/cos | 2 scale | 3 legacy P+ofs*S |
//      4 fused P|S: bz==0 -> C = scp[h]*acc (A=Av); bz==1 -> A=Pprev(f16),
//        C(+sCh) = ofp[h]*scp[h]*acc, nout = ||acc_row||/L.
template<int BM, int BN, int AMODE, int SECSH, int EPI, typename OUT_T>
__global__ __launch_bounds__(256) void gemm_bt_k(
    const void* __restrict__ Av, const _Float16* __restrict__ BT,
    OUT_T* __restrict__ C, int K, int lda, int ldb, int ldc,
    long sAb, long sAh, long sBb, long sBh, long sCb, long sCh,
    const float* __restrict__ norms, const float* __restrict__ scp,
    const float* __restrict__ ofp, const float* __restrict__ Pprev,
    float* __restrict__ nout)
{
  __shared__ __align__(16) _Float16 sA[BM * 64];
  __shared__ __align__(16) _Float16 sB[BN * 64];
  const int t = threadIdx.x;
  const int lane = t & 63;
  const int w = t >> 6;
  const int wm = w >> 1, wn = w & 1;
  const int by = blockIdx.x, bx = blockIdx.y, bz = blockIdx.z;
  long aoff = (long)(bz >> 4) * sAb + (long)(bz & 15) * sAh;
  BT += (long)(bz >> 4) * sBb + (long)(bz & 15) * sBh;
  C  += (long)(bz >> 4) * sCb + (long)(bz & 15) * sCh;
  const _Float16* A16 = (const _Float16*)Av + aoff;
  const float*    A32 = (const float*)Av + aoff;
  if constexpr (EPI == 4) {               // fused P|S: z=1 reads slopes side
    if (bz & 15) {
      if constexpr (AMODE == 4) A16 = (const _Float16*)Pprev + aoff;
      else                      A32 = Pprev + aoff;
    }
  }
  constexpr int WTM = BM / 32, WTN = BN / 32;
  fx4 acc[WTM][WTN];
#pragma unroll
  for (int i = 0; i < WTM; ++i)
#pragma unroll
    for (int j = 0; j < WTN; ++j) acc[i][j] = (fx4){0.f, 0.f, 0.f, 0.f};

  for (int k0 = 0; k0 < K; k0 += 64) {
    __syncthreads();
    // ---- stage A tile [BM x 64] ----
    if constexpr (AMODE == 0 || AMODE == 4) {
      int cb;
      if constexpr (AMODE == 4) {
        int sec = k0 >> SECSH;
        cb = (k0 & ((1 << SECSH) - 1)) + (sec == 1 ? (1 << SECSH) : 0);
      } else cb = k0;
#pragma unroll
      for (int i = 0; i < BM / 32; ++i) {
        int s = i * 256 + t; int row = s >> 3; int kc = (s & 7) ^ (row & 7);
        g2l16(&A16[(long)(by * BM + row) * lda + cb + kc * 8],
              &sA[(long)(i * 256 + (w << 6)) * 8]);
      }
    } else {
      int mode, cs;
      if constexpr (AMODE >= 2) { mode = k0 >> SECSH; cs = k0 & ((1 << SECSH) - 1); }
      else                      { mode = 0;           cs = k0;                      }
#pragma unroll
      for (int i = 0; i < BM / 32; ++i) {
        int s = i * 256 + t; int row = s >> 3; int kc = (s & 7) ^ (row & 7);
        const float* src = A32 + (long)(by * BM + row) * lda + cs + kc * 8;
        fx4 v0 = *(const fx4*)src;
        fx4 v1 = *(const fx4*)(src + 4);
        if constexpr (AMODE == 3) {
          if (bz & 15) {                  // k'-pass: kp = P + (offs*scale*S)
            const float* src2 = src + sAb;
            fx4 w0 = *(const fx4*)src2;
            fx4 w1 = *(const fx4*)(src2 + 4);
#pragma unroll
            for (int e = 0; e < 4; ++e) { v0[e] += w0[e]; v1[e] += w1[e]; }
          }
        }
        hx8 hv;
        if (mode != 1) {
#pragma unroll
          for (int e = 0; e < 4; ++e) { hv[e] = (_Float16)v0[e]; hv[4 + e] = (_Float16)v1[e]; }
        } else {
#pragma unroll
          for (int e = 0; e < 4; ++e) {
            _Float16 h0 = (_Float16)v0[e]; hv[e]     = (_Float16)(v0[e] - (float)h0);
            _Float16 h1 = (_Float16)v1[e]; hv[4 + e] = (_Float16)(v1[e] - (float)h1);
          }
        }
        *(hx8*)&sA[s * 8] = hv;
      }
    }
    // ---- stage B tile [BN x 64] via global_load_lds (all modes) ----
#pragma unroll
    for (int i = 0; i < BN / 32; ++i) {
      int s = i * 256 + t; int row = s >> 3; int kc = (s & 7) ^ (row & 7);
      g2l16(&BT[(long)(bx * BN + row) * ldb + k0 + kc * 8],
            &sB[(long)(i * 256 + (w << 6)) * 8]);
    }
    __syncthreads();
#pragma unroll
    for (int kk = 0; kk < 64; kk += 32) {
      hx8 af[WTM], bf[WTN];
      int kcb = (kk >> 3) + (lane >> 4);
#pragma unroll
      for (int i = 0; i < WTM; ++i) {
        int r = wm * (BM / 2) + i * 16 + (lane & 15);
        af[i] = *(const hx8*)&sA[(r * 8 + (kcb ^ (r & 7))) * 8];
      }
#pragma unroll
      for (int j = 0; j < WTN; ++j) {
        int r = wn * (BN / 2) + j * 16 + (lane & 15);
        bf[j] = *(const hx8*)&sB[(r * 8 + (kcb ^ (r & 7))) * 8];
      }
#pragma unroll
      for (int i = 0; i < WTM; ++i)
#pragma unroll
        for (int j = 0; j < WTN; ++j)
          acc[i][j] = __builtin_amdgcn_mfma_f32_16x16x32_f16(af[i], bf[j], acc[i][j], 0, 0, 0);
    }
  }
  if constexpr (EPI == 0) {
#pragma unroll
    for (int i = 0; i < WTM; ++i) {
#pragma unroll
      for (int j = 0; j < WTN; ++j) {
        int rowb = by * BM + wm * (BM / 2) + i * 16 + ((lane >> 4) << 2);
        int col  = bx * BN + wn * (BN / 2) + j * 16 + (lane & 15);
#pragma unroll
        for (int r = 0; r < 4; ++r)
          C[(long)(rowb + r) * ldc + col] = (OUT_T)acc[i][j][r];
      }
    }
  } else if constexpr (EPI == 1) {
    const float inv2pi = 0.15915494309189535f;
    const float ratio  = 0.08838834764831845f;   // 1/sqrt(128)
    const bool useN = ((bz & 15) == 0);
#pragma unroll
    for (int i = 0; i < WTM; ++i) {
#pragma unroll
      for (int j = 0; j < WTN; ++j) {
        int rowb = by * BM + wm * (BM / 2) + i * 16 + ((lane >> 4) << 2);
        int col  = bx * BN + wn * (BN / 2) + j * 16 + (lane & 15);
#pragma unroll
        for (int r = 0; r < 4; ++r) {
          int row = rowb + r;                     // row = l*16 + h
          float rn = ratio * (useN ? norms[row] : 1.0f);
          long ob = ((long)(row & 15) * 4096 + (row >> 4)) * 256;
          float v = acc[i][j][r] * inv2pi;
          v -= floorf(v);                         // revolutions in [0,1)
          C[ob + col]       = (OUT_T)(rn * __builtin_amdgcn_sinf(v));
          C[ob + 128 + col] = (OUT_T)(rn * __builtin_amdgcn_cosf(v));
        }
      }
    }
  } else if constexpr (EPI == 2) {
    const int h = ((bx * BN) >> 6) + wn;          // BN=128: 2 heads/block
    const float sc = scp[h];
#pragma unroll
    for (int i = 0; i < WTM; ++i) {
#pragma unroll
      for (int j = 0; j < WTN; ++j) {
        int rowb = by * BM + wm * (BM / 2) + i * 16 + ((lane >> 4) << 2);
        int col  = bx * BN + wn * (BN / 2) + j * 16 + (lane & 15);
#pragma unroll
        for (int r = 0; r < 4; ++r)
          C[(long)(rowb + r) * ldc + col] = (OUT_T)(sc * acc[i][j][r]);
      }
    }
  } else {                                        // EPI == 4: fused P|S
    const int h = ((bx * BN) >> 6) + wn;
    const float sc = scp[h];
    if ((bz & 15) == 0) {                         // P: C = scale*acc
#pragma unroll
      for (int i = 0; i < WTM; ++i) {
#pragma unroll
        for (int j = 0; j < WTN; ++j) {
          int rowb = by * BM + wm * (BM / 2) + i * 16 + ((lane >> 4) << 2);
          int col  = bx * BN + wn * (BN / 2) + j * 16 + (lane & 15);
#pragma unroll
          for (int r = 0; r < 4; ++r)
            C[(long)(rowb + r) * ldc + col] = (OUT_T)(sc * acc[i][j][r]);
        }
      }
    } else {                                      // S: C = offs*scale*acc, norms
      const float osc = ofp[h] * sc;
#pragma unroll
      for (int i = 0; i < WTM; ++i) {
        float sq[4] = {0.f, 0.f, 0.f, 0.f};
        int rowb = by * BM + wm * (BM / 2) + i * 16 + ((lane >> 4) << 2);
#pragma unroll
        for (int j = 0; j < WTN; ++j) {
          int col = bx * BN + wn * (BN / 2) + j * 16 + (lane & 15);
#pragma unroll
          for (int r = 0; r < 4; ++r) {
            float a = acc[i][j][r];
            sq[r] += a * a;
            C[(long)(rowb + r) * ldc + col] = (OUT_T)(osc * a);
          }
        }
#pragma unroll
        for (int r = 0; r < 4; ++r) {             // 64-col norm: 4 j's x 16 lanes
          float s = sq[r];
          s += __shfl_xor(s, 1); s += __shfl_xor(s, 2);
          s += __shfl_xor(s, 4); s += __shfl_xor(s, 8);
          if ((lane & 15) == 0)
            nout[(long)(rowb + r) * 16 + h] = sqrtf(s) * (1.0f / 4096.0f);
        }
      }
    }
  }
}

// ---------------- kv kernel (per-b): kvT[d][m] = sum_l v[l][d] * k'[l][m] ---
__global__ __launch_bounds__(256) void kv_k(const _Float16* __restrict__ Kp,
                                            const _Float16* __restrict__ Vhb,
                                            float* __restrict__ kvacc)
{
  __shared__ __align__(16) _Float16 sK[256 * 72];   // [m][l] stride 72
  __shared__ __align__(16) _Float16 sV[64 * 72];    // [d][l]
  const int t = threadIdx.x, lane = t & 63, w = t >> 6;
  const int h = blockIdx.x;
  const int l0 = blockIdx.y * (L_ / KV_SPLIT);
  fx4 acc[4][4];
#pragma unroll
  for (int i = 0; i < 4; ++i)
#pragma unroll
    for (int j = 0; j < 4; ++j) acc[i][j] = (fx4){0.f, 0.f, 0.f, 0.f};
  const _Float16* Kbase = Kp + (long)h * L_ * 256;
  for (int kt = 0; kt < L_ / KV_SPLIT; kt += 64) {
    __syncthreads();
#pragma unroll
    for (int i = 0; i < 8; ++i) {               // k' tile: 64 l x 256 m, transpose
      int mc = w + 4 * i;                       // 0..31 (wave-uniform)
      hx8 vv = *(const hx8*)&Kbase[(long)(l0 + kt + lane) * 256 + mc * 8];
#pragma unroll
      for (int e = 0; e < 8; ++e) sK[(mc * 8 + e) * 72 + lane] = vv[e];
    }
#pragma unroll
    for (int i = 0; i < 2; ++i) {               // v tile: 64 l x 64 d, transpose
      int dc = w + 4 * i;                       // 0..7
      hx8 vv = *(const hx8*)&Vhb[(long)(l0 + kt + lane) * 1024 + h * 64 + dc * 8];
#pragma unroll
      for (int e = 0; e < 8; ++e) sV[(dc * 8 + e) * 72 + lane] = vv[e];
    }
    __syncthreads();
#pragma unroll
    for (int kk = 0; kk < 64; kk += 32) {
      hx8 af[4], bf[4];
      int lfr = kk + ((lane >> 4) << 3);
#pragma unroll
      for (int i = 0; i < 4; ++i)
        af[i] = *(const hx8*)&sV[(i * 16 + (lane & 15)) * 72 + lfr];
#pragma unroll
      for (int j = 0; j < 4; ++j)
        bf[j] = *(const hx8*)&sK[(w * 64 + j * 16 + (lane & 15)) * 72 + lfr];
#pragma unroll
      for (int i = 0; i < 4; ++i)
#pragma unroll
        for (int j = 0; j < 4; ++j)
          acc[i][j] = __builtin_amdgcn_mfma_f32_16x16x32_f16(af[i], bf[j], acc[i][j], 0, 0, 0);
    }
  }
  float* obase = kvacc + (long)h * (64 * 256);
#pragma unroll
  for (int i = 0; i < 4; ++i)
#pragma unroll
    for (int j = 0; j < 4; ++j) {
      int d0 = i * 16 + ((lane >> 4) << 2);
      int m  = w * 64 + j * 16 + (lane & 15);
#pragma unroll
      for (int r = 0; r < 4; ++r)
        atomicAdd(&obase[(long)(d0 + r) * 256 + m], acc[i][j][r]);
    }
}

// ---------------------------------------------------------------------------
extern "C" void kernel_launch(void* const* d_in, const int* in_sizes, int n_in,
                              void* d_out, int out_size, void* d_ws, size_t ws_size,
                              hipStream_t stream) {
  const float* x     = (const float*)d_in[0];
  const float* pos   = (const float*)d_in[1];
  const float* slp   = (const float*)d_in[2];
  const float* Wv    = (const float*)d_in[3];
  const float* Wo    = (const float*)d_in[4];
  const float* Wpf   = (const float*)d_in[5];
  const float* scale = (const float*)d_in[6];
  const float* offs  = (const float*)d_in[7];
  const float* proj  = (const float*)d_in[8];
  float* out = (float*)d_out;
  char* ws = (char*)d_ws;

  // Arena ~218.6 MB, unchanged. Aliases (stream-order-safe):
  //   ph2 = qpr, sh2 = kpr  (f16 [hi|lo] pos/slp, dead once P|S GEMM reads
  //   them; fourier overwrites qpr/kpr only after that)
  //   xh = Zb               (x as f16; dead after V GEMM, before z writes Zb)
  // NOTE: Sb must follow Pb contiguously; kpr must follow qpr contiguously.
  size_t o = 0;
  auto alloc = [&](size_t bytes) { char* p = ws + o; o += (bytes + 255) & ~(size_t)255; return p; };
  float*    Pb     = (float*)alloc(33554432);      // [2][4096][1024] f32 (= qp, scaled)
  float*    Sb     = (float*)alloc(33554432);      // (= offs*scale*slope_proj) == Pb + 8388608
  _Float16* qpr    = (_Float16*)alloc(33554432);   // per-b [H][L][256] f16
  _Float16* kpr    = (_Float16*)alloc(33554432);   //                 == qpr + 16777216
  _Float16* Vh     = (_Float16*)alloc(33554432);   // [BL][1024] f16
  _Float16* Zb     = (_Float16*)alloc(33554432);   // [BL][1024] f16
  _Float16* WvT    = (_Float16*)alloc(2097152);
  _Float16* WoT    = (_Float16*)alloc(2097152);
  _Float16* Wpf3T  = (_Float16*)alloc(6291456);    // [1024][3072] [hi;hi;lo]
  _Float16* proj3T = (_Float16*)alloc(49152);      // [128][192] [hi|hi|lo]
  float*    normsB = (float*)alloc(524288);        // [8192][16] f32 per super-batch
  float*    kvacc  = (float*)alloc(4194304);       // [BH][64][256] f32
  _Float16* kvh    = (_Float16*)alloc(2097152);
  _Float16* ph2 = qpr;                             // [8192][2048] f16 [hi|lo]
  _Float16* sh2 = kpr;
  _Float16* xh  = Zb;                              // [16384][1024] f16
  (void)ws_size; (void)in_sizes; (void)n_in; (void)out_size;

  // prep
  wt_k<<<dim3(16, 16), 256, 0, stream>>>(Wv, WvT);
  wt_k<<<dim3(16, 16), 256, 0, stream>>>(Wo, WoT);
  wpf3_k<<<dim3(16, 16), 256, 0, stream>>>(Wpf, Wpf3T);
  proj3_k<<<32, 256, 0, stream>>>(proj, proj3T);
  zero_k<<<256, 256, 0, stream>>>(kvacc, 262144);
  cvt16_k<<<8192, 256, 0, stream>>>(x, xh, 2097152);

  // V = xh @ W_v (pure f16, gload_lds staging), M=16384, grid (M,N)-swapped
  gemm_bt_k<128, 128, 0, 0, 0, _Float16><<<dim3(128, 8, 1), 256, 0, stream>>>(
      xh, WvT, Vh, 1024, 1024, 1024, 1024, 0, 0, 0, 0, 0, 0,
      nullptr, nullptr, nullptr, nullptr, nullptr);

  for (int sb = 0; sb < 2; ++sb) {
    const float* pos_sb = pos + (long)sb * 8192 * 1024;
    const float* slp_sb = slp + (long)sb * 8192 * 1024;
    // pre-split pos/slp to f16 [hi|lo] (one pass; conversion leaves the k-loop)
    cvt_hilo_k<<<4096, 256, 0, stream>>>(pos_sb, ph2);
    cvt_hilo_k<<<4096, 256, 0, stream>>>(slp_sb, sh2);
    // Fused P|S: z=0 -> Pb = scale*(pos@W); z=1 -> Sb = offs*scale*(slp@W)
    // (+ slope norms). AMODE=4: A f16 pre-split, gload_lds; virtual K=3072.
    gemm_bt_k<128, 128, 4, 10, 4, float><<<dim3(64, 8, 2), 256, 0, stream>>>(
        ph2, Wpf3T, Pb, 3072, 2048, 3072, 1024, 0, 0, 0, 0, 0, 8388608L,
        nullptr, scale, offs, (const float*)sh2, normsB);

    for (int bb = 0; bb < 2; ++bb) {
      int b = sb * 2 + bb;
      _Float16* Vh_b  = Vh + (long)b * L_ * 1024;
      _Float16* Zb_b  = Zb + (long)b * L_ * 1024;
      float* kvacc_b  = kvacc + (long)b * H_ * 64 * 256;
      _Float16* kvh_b = kvh   + (long)b * H_ * 64 * 256;
      // fourier q (bz=0, A=Pb_b, norms) + k (bz=1, A=Pb_b + Sb_b combined in
      // staging via sAb=+8388608) in one launch; K=192 split-f16 vs proj3T;
      // M=65536 rows of [l*16+h][64]. (Overwrites ph2/sh2 — already consumed.)
      gemm_bt_k<128, 128, 3, 6, 1, _Float16><<<dim3(512, 1, 2), 256, 0, stream>>>(
          Pb + (long)bb * 4194304, proj3T, qpr, 192, 64, 192, 0,
          8388608L, 0L, 0, 0, 0, 16777216L,
          normsB + (long)bb * 65536, nullptr, nullptr, nullptr, nullptr);
      // kv (split-K=16 over L with atomics) -> kvacc_b; cast to f16
      kv_k<<<dim3(16, KV_SPLIT), 256, 0, stream>>>(kpr, Vh_b, kvacc_b);
      cast_out_f16_k<<<1024, 256, 0, stream>>>(kvacc_b, kvh_b, 262144);
      // z = q'' @ kvT (batched over h), C -> Zb_b [L][1024]
      gemm_bt_k<128, 64, 0, 0, 0, _Float16><<<dim3(32, 1, 16), 256, 0, stream>>>(
          qpr, kvh_b, Zb_b, 256, 256, 256, 1024,
          0L, (long)L_ * 256, 0L, 16384L, 0L, 64L,
          nullptr, nullptr, nullptr, nullptr, nullptr);
    }
  }
  // out = z @ W_o (f32 out), M=16384
  gemm_bt_k<128, 128, 0, 0, 0, float><<<dim3(128, 8, 1), 256, 0, stream>>>(
      Zb, WoT, out, 1024, 1024, 1024, 1024, 0, 0, 0, 0, 0, 0,
      nullptr, nullptr, nullptr, nullptr, nullptr);
}

// Round 3
// 896.682 us; speedup vs baseline: 1.2520x; 1.0520x over previous
//
#include <hip/hip_runtime.h>
#include <hip/hip_bf16.h>
#include <stdint.h>

// ---------------------------------------------------------------------------
// LinearSelfAttention (Performer-style) on gfx950.
//   pre:  pos/slp -> f16 [hi|lo] (aliased onto qpr/kpr), x -> f16 (Zb)
//   V     = x16 @ W_v                   (f16 MFMA, global_load_lds staging)
//   P|S   = pos/slp @ W_pf              (pre-split f16, virtual K=3072, one
//           dispatch z=2). Epilogue now writes f16 [hi|lo] pairs (Pb2/Sb2).
//   q',k' = pure-f16 MFMA GEMM vs proj6T (AMODE=5): q-side K=192 {Ph,Pl,Ph},
//           k-side K=384 adds {Sh,Sl,Sh} — kp-combine via MFMA linearity,
//           gload_lds staging, A-traffic halved. sin/cos epilogue.
//   kvT   = sum_l v[l][d] k'[l][m]      (f16 MFMA; NEW: 4x8 reg-transpose ->
//           ds_write_b64 with XOR bank-swizzle, 4x fewer DS ops)
//   z     = q'' @ kvT                   (batched f16 MFMA)
//   out   = z @ W_o                     (f16 MFMA, f32 out)
// R6 basis: P|S at its structure ceiling (30% Mfma / 39% VALU); remaining
// ~590us is the fourier (f32 reg-staging + in-loop cvt) and kv (scalar b16
// LDS transpose) tail. Workspace unchanged: 218.6 MB.
// ---------------------------------------------------------------------------

typedef _Float16 hx8 __attribute__((ext_vector_type(8)));
typedef _Float16 hx4 __attribute__((ext_vector_type(4)));
typedef float    fx4 __attribute__((ext_vector_type(4)));

#define H_   16
#define D_   64
#define L_   4096
#define B_   4
#define KV_SPLIT 16

// global -> LDS direct (16B/lane). LDS dest wave-uniform; HW adds lane*16.
__device__ __forceinline__ void g2l16(const _Float16* g, _Float16* l) {
  __builtin_amdgcn_global_load_lds(
      (const __attribute__((address_space(1))) void*)g,
      (__attribute__((address_space(3))) void*)l, 16, 0, 0);
}

// ---------------- prep kernels ----------------
// W [1024][1024] f32 -> WT [1024][1024] f16 (WT[n][k] = W[k][n])
__global__ __launch_bounds__(256) void wt_k(const float* __restrict__ W,
                                            _Float16* __restrict__ WT) {
  __shared__ float tile[64][65];
  int t = threadIdx.x; int c = t & 63; int r0 = t >> 6;
  int bx = blockIdx.x * 64, by = blockIdx.y * 64;
  for (int r = r0; r < 64; r += 4) tile[r][c] = W[(long)(by + r) * 1024 + bx + c];
  __syncthreads();
  for (int r = r0; r < 64; r += 4)
    WT[(long)(bx + r) * 1024 + by + c] = (_Float16)tile[c][r];
}

// W_pf -> WT3 [1024][3072] f16 sections: [hi ; hi ; lo] (transposed)
__global__ __launch_bounds__(256) void wpf3_k(const float* __restrict__ W,
                                              _Float16* __restrict__ WT3) {
  __shared__ float tile[64][65];
  int t = threadIdx.x; int c = t & 63; int r0 = t >> 6;
  int bx = blockIdx.x * 64, by = blockIdx.y * 64;
  for (int r = r0; r < 64; r += 4) tile[r][c] = W[(long)(by + r) * 1024 + bx + c];
  __syncthreads();
  for (int r = r0; r < 64; r += 4) {
    float x = tile[c][r];
    _Float16 hi = (_Float16)x;
    _Float16 lo = (_Float16)(x - (float)hi);
    long base = (long)(bx + r) * 3072 + by + c;
    WT3[base] = hi; WT3[base + 1024] = hi; WT3[base + 2048] = lo;
  }
}

// proj [128][64] f32 -> proj6T [128][384] f16 [hi|hi|lo|hi|hi|lo], cnorm folded
__global__ __launch_bounds__(256) void proj6_k(const float* __restrict__ proj,
                                               _Float16* __restrict__ proj6T) {
  int i = blockIdx.x * 256 + threadIdx.x;
  if (i >= 8192) return;
  int m = i >> 6, d = i & 63;
  float p = 0.35355339059327373f * proj[i];    // 1/64^0.25 folded
  _Float16 hi = (_Float16)p;
  _Float16 lo = (_Float16)(p - (float)hi);
  long b = (long)m * 384 + d;
  proj6T[b]       = hi; proj6T[b + 64]  = hi; proj6T[b + 128] = lo;
  proj6T[b + 192] = hi; proj6T[b + 256] = hi; proj6T[b + 320] = lo;
}

__global__ __launch_bounds__(256) void zero_k(float* __restrict__ p, int n4) {
  int i = blockIdx.x * 256 + threadIdx.x;
  int stride = gridDim.x * 256;
  fx4 z = {0.f, 0.f, 0.f, 0.f};
  for (; i < n4; i += stride) ((fx4*)p)[i] = z;
}

__global__ __launch_bounds__(256) void cast_out_f16_k(const float* __restrict__ in,
                                                      _Float16* __restrict__ out, int n) {
  int i = blockIdx.x * 256 + threadIdx.x;
  int stride = gridDim.x * 256;
  for (; i < n; i += stride) out[i] = (_Float16)in[i];
}

// [8192][1024] f32 -> [8192][2048] f16 [hi|lo]. 4096 blocks x 256 thr.
__global__ __launch_bounds__(256) void cvt_hilo_k(const float* __restrict__ in,
                                                  _Float16* __restrict__ out) {
  long i = (long)blockIdx.x * 256 + threadIdx.x;
  long idx = i * 8;
  int row = (int)(idx >> 10), c = (int)(idx & 1023);
  fx4 a = *(const fx4*)&in[idx];
  fx4 b = *(const fx4*)&in[idx + 4];
  hx8 hi, lo;
#pragma unroll
  for (int e = 0; e < 4; ++e) {
    _Float16 h0 = (_Float16)a[e]; hi[e] = h0;     lo[e]     = (_Float16)(a[e] - (float)h0);
    _Float16 h1 = (_Float16)b[e]; hi[4 + e] = h1; lo[4 + e] = (_Float16)(b[e] - (float)h1);
  }
  *(hx8*)&out[(long)row * 2048 + c]        = hi;
  *(hx8*)&out[(long)row * 2048 + 1024 + c] = lo;
}

// plain f32 -> f16 cast, 8/thread vectorized
__global__ __launch_bounds__(256) void cvt16_k(const float* __restrict__ in,
                                               _Float16* __restrict__ out, long n8) {
  long i = (long)blockIdx.x * 256 + threadIdx.x;
  if (i >= n8) return;
  long idx = i * 8;
  fx4 a = *(const fx4*)&in[idx];
  fx4 b = *(const fx4*)&in[idx + 4];
  hx8 h;
#pragma unroll
  for (int e = 0; e < 4; ++e) { h[e] = (_Float16)a[e]; h[4 + e] = (_Float16)b[e]; }
  *(hx8*)&out[idx] = h;
}

// ---------------- generic f16 MFMA GEMM:  C[M][N] = A[M][K] @ BT[N][K]^T ----
// BK=64, 256 threads, 4 waves 2x2; XOR-swizzled LDS (conflict-free b128).
// AMODE: 0 = A f16 gload_lds; 1/2/3 legacy reg-path (unused);
//        4 = A f16 pre-split [hi|lo] (lda=2*(1<<SECSH)), gload_lds,
//            section map k0 -> {hi, lo, hi};
//        5 = fourier A: f16 [hi64|lo64] rows (lda=128), sections (SECSH=6):
//            {Ph,Pl,Ph,Sh,Sl,Sh}, S-buffer at A16+sAb; q-side (bz&1==0)
//            runs only K/2 (first 3 sections).
// EPI: 0 plain | 1 fourier sin/cos (norms if (bz&15)==0) | 2 scale |
//      4 fused P|S: bz==0 -> Pb2 f16 hi|lo = scp[h]*acc; bz==1 -> A=Pprev,
//        Sb2(+sCh) f16 hi|lo = ofp[h]*scp[h]*acc, nout = ||acc_row||/L.
template<int BM, int BN, int AMODE, int SECSH, int EPI, typename OUT_T>
__global__ __launch_bounds__(256) void gemm_bt_k(
    const void* __restrict__ Av, const _Float16* __restrict__ BT,
    OUT_T* __restrict__ C, int K, int lda, int ldb, int ldc,
    long sAb, long sAh, long sBb, long sBh, long sCb, long sCh,
    const float* __restrict__ norms, const float* __restrict__ scp,
    const float* __restrict__ ofp, const float* __restrict__ Pprev,
    float* __restrict__ nout)
{
  __shared__ __align__(16) _Float16 sA[BM * 64];
  __shared__ __align__(16) _Float16 sB[BN * 64];
  const int t = threadIdx.x;
  const int lane = t & 63;
  const int w = t >> 6;
  const int wm = w >> 1, wn = w & 1;
  const int by = blockIdx.x, bx = blockIdx.y, bz = blockIdx.z;
  long aoff = (long)(bz >> 4) * sAb + (long)(bz & 15) * sAh;
  if constexpr (AMODE == 5) aoff = 0;   // sAb reused as S-buffer offset
  BT += (long)(bz >> 4) * sBb + (long)(bz & 15) * sBh;
  C  += (long)(bz >> 4) * sCb + (long)(bz & 15) * sCh;
  const _Float16* A16 = (const _Float16*)Av + aoff;
  const float*    A32 = (const float*)Av + aoff;
  if constexpr (EPI == 4) {               // fused P|S: z=1 reads slopes side
    if (bz & 15) A16 = (const _Float16*)Pprev + aoff;
  }
  constexpr int WTM = BM / 32, WTN = BN / 32;
  fx4 acc[WTM][WTN];
#pragma unroll
  for (int i = 0; i < WTM; ++i)
#pragma unroll
    for (int j = 0; j < WTN; ++j) acc[i][j] = (fx4){0.f, 0.f, 0.f, 0.f};

  int Klim = K;
  if constexpr (AMODE == 5) { if ((bz & 1) == 0) Klim >>= 1; }

  for (int k0 = 0; k0 < Klim; k0 += 64) {
    __syncthreads();
    // ---- stage A tile [BM x 64] ----
    if constexpr (AMODE == 0 || AMODE == 4 || AMODE == 5) {
      long cb;
      if constexpr (AMODE == 4) {
        int sec = k0 >> SECSH;
        cb = (k0 & ((1 << SECSH) - 1)) + (sec == 1 ? (1 << SECSH) : 0);
      } else if constexpr (AMODE == 5) {
        int sec = k0 >> SECSH;
        cb = ((sec == 1 || sec == 4) ? 64 : 0) + ((sec >= 3) ? sAb : 0);
      } else cb = k0;
#pragma unroll
      for (int i = 0; i < BM / 32; ++i) {
        int s = i * 256 + t; int row = s >> 3; int kc = (s & 7) ^ (row & 7);
        g2l16(&A16[(long)(by * BM + row) * lda + cb + kc * 8],
              &sA[(long)(i * 256 + (w << 6)) * 8]);
      }
    } else {
      // legacy f32 reg path (unused by current instantiations)
      int mode, cs;
      if constexpr (AMODE >= 2) { mode = k0 >> SECSH; cs = k0 & ((1 << SECSH) - 1); }
      else                      { mode = 0;           cs = k0;                      }
#pragma unroll
      for (int i = 0; i < BM / 32; ++i) {
        int s = i * 256 + t; int row = s >> 3; int kc = (s & 7) ^ (row & 7);
        const float* src = A32 + (long)(by * BM + row) * lda + cs + kc * 8;
        fx4 v0 = *(const fx4*)src;
        fx4 v1 = *(const fx4*)(src + 4);
        if constexpr (AMODE == 3) {
          if (bz & 15) {
            const float* src2 = src + sAb;
            fx4 w0 = *(const fx4*)src2;
            fx4 w1 = *(const fx4*)(src2 + 4);
#pragma unroll
            for (int e = 0; e < 4; ++e) { v0[e] += w0[e]; v1[e] += w1[e]; }
          }
        }
        hx8 hv;
        if (mode != 1) {
#pragma unroll
          for (int e = 0; e < 4; ++e) { hv[e] = (_Float16)v0[e]; hv[4 + e] = (_Float16)v1[e]; }
        } else {
#pragma unroll
          for (int e = 0; e < 4; ++e) {
            _Float16 h0 = (_Float16)v0[e]; hv[e]     = (_Float16)(v0[e] - (float)h0);
            _Float16 h1 = (_Float16)v1[e]; hv[4 + e] = (_Float16)(v1[e] - (float)h1);
          }
        }
        *(hx8*)&sA[s * 8] = hv;
      }
    }
    // ---- stage B tile [BN x 64] via global_load_lds ----
#pragma unroll
    for (int i = 0; i < BN / 32; ++i) {
      int s = i * 256 + t; int row = s >> 3; int kc = (s & 7) ^ (row & 7);
      g2l16(&BT[(long)(bx * BN + row) * ldb + k0 + kc * 8],
            &sB[(long)(i * 256 + (w << 6)) * 8]);
    }
    __syncthreads();
#pragma unroll
    for (int kk = 0; kk < 64; kk += 32) {
      hx8 af[WTM], bf[WTN];
      int kcb = (kk >> 3) + (lane >> 4);
#pragma unroll
      for (int i = 0; i < WTM; ++i) {
        int r = wm * (BM / 2) + i * 16 + (lane & 15);
        af[i] = *(const hx8*)&sA[(r * 8 + (kcb ^ (r & 7))) * 8];
      }
#pragma unroll
      for (int j = 0; j < WTN; ++j) {
        int r = wn * (BN / 2) + j * 16 + (lane & 15);
        bf[j] = *(const hx8*)&sB[(r * 8 + (kcb ^ (r & 7))) * 8];
      }
#pragma unroll
      for (int i = 0; i < WTM; ++i)
#pragma unroll
        for (int j = 0; j < WTN; ++j)
          acc[i][j] = __builtin_amdgcn_mfma_f32_16x16x32_f16(af[i], bf[j], acc[i][j], 0, 0, 0);
    }
  }
  if constexpr (EPI == 0) {
#pragma unroll
    for (int i = 0; i < WTM; ++i) {
#pragma unroll
      for (int j = 0; j < WTN; ++j) {
        int rowb = by * BM + wm * (BM / 2) + i * 16 + ((lane >> 4) << 2);
        int col  = bx * BN + wn * (BN / 2) + j * 16 + (lane & 15);
#pragma unroll
        for (int r = 0; r < 4; ++r)
          C[(long)(rowb + r) * ldc + col] = (OUT_T)acc[i][j][r];
      }
    }
  } else if constexpr (EPI == 1) {
    const float inv2pi = 0.15915494309189535f;
    const float ratio  = 0.08838834764831845f;   // 1/sqrt(128)
    const bool useN = ((bz & 15) == 0);
#pragma unroll
    for (int i = 0; i < WTM; ++i) {
#pragma unroll
      for (int j = 0; j < WTN; ++j) {
        int rowb = by * BM + wm * (BM / 2) + i * 16 + ((lane >> 4) << 2);
        int col  = bx * BN + wn * (BN / 2) + j * 16 + (lane & 15);
#pragma unroll
        for (int r = 0; r < 4; ++r) {
          int row = rowb + r;                     // row = l*16 + h
          float rn = ratio * (useN ? norms[row] : 1.0f);
          long ob = ((long)(row & 15) * 4096 + (row >> 4)) * 256;
          float v = acc[i][j][r] * inv2pi;
          v -= floorf(v);                         // revolutions in [0,1)
          C[ob + col]       = (OUT_T)(rn * __builtin_amdgcn_sinf(v));
          C[ob + 128 + col] = (OUT_T)(rn * __builtin_amdgcn_cosf(v));
        }
      }
    }
  } else if constexpr (EPI == 2) {
    const int h = ((bx * BN) >> 6) + wn;
    const float sc = scp[h];
#pragma unroll
    for (int i = 0; i < WTM; ++i) {
#pragma unroll
      for (int j = 0; j < WTN; ++j) {
        int rowb = by * BM + wm * (BM / 2) + i * 16 + ((lane >> 4) << 2);
        int col  = bx * BN + wn * (BN / 2) + j * 16 + (lane & 15);
#pragma unroll
        for (int r = 0; r < 4; ++r)
          C[(long)(rowb + r) * ldc + col] = (OUT_T)(sc * acc[i][j][r]);
      }
    }
  } else {                                        // EPI == 4: fused P|S, f16 hi|lo out
    const int h = ((bx * BN) >> 6) + wn;          // BN=128: 2 heads/block, wave-uniform
    const float sc = scp[h];
    _Float16* C16 = (_Float16*)C;
    if ((bz & 15) == 0) {                         // P: Pb2 = hi|lo of scale*acc
#pragma unroll
      for (int i = 0; i < WTM; ++i) {
#pragma unroll
        for (int j = 0; j < WTN; ++j) {
          int rowb = by * BM + wm * (BM / 2) + i * 16 + ((lane >> 4) << 2);
          int d    = wn * 0 + j * 16 + (lane & 15);   // col & 63
#pragma unroll
          for (int r = 0; r < 4; ++r) {
            float v = sc * acc[i][j][r];
            long a = ((long)(rowb + r) * 16 + h) * 128 + d;
            _Float16 hi = (_Float16)v;
            C16[a]      = hi;
            C16[a + 64] = (_Float16)(v - (float)hi);
          }
        }
      }
    } else {                                      // S: Sb2 = hi|lo of offs*scale*acc
      const float osc = ofp[h] * sc;
#pragma unroll
      for (int i = 0; i < WTM; ++i) {
        float sq[4] = {0.f, 0.f, 0.f, 0.f};
        int rowb = by * BM + wm * (BM / 2) + i * 16 + ((lane >> 4) << 2);
#pragma unroll
        for (int j = 0; j < WTN; ++j) {
          int d = j * 16 + (lane & 15);
#pragma unroll
          for (int r = 0; r < 4; ++r) {
            float a0 = acc[i][j][r];
            sq[r] += a0 * a0;
            float v = osc * a0;
            long a = ((long)(rowb + r) * 16 + h) * 128 + d;
            _Float16 hi = (_Float16)v;
            C16[a]      = hi;
            C16[a + 64] = (_Float16)(v - (float)hi);
          }
        }
#pragma unroll
        for (int r = 0; r < 4; ++r) {             // 64-col norm: 4 j's x 16 lanes
          float s = sq[r];
          s += __shfl_xor(s, 1); s += __shfl_xor(s, 2);
          s += __shfl_xor(s, 4); s += __shfl_xor(s, 8);
          if ((lane & 15) == 0)
            nout[(long)(rowb + r) * 16 + h] = sqrtf(s) * (1.0f / 4096.0f);
        }
      }
    }
  }
}

// ---------------- kv kernel (per-b): kvT[d][m] = sum_l v[l][d] * k'[l][m] ---
// Staging: 4x8 register transpose -> ds_write_b64, XOR bank-swizzle
// byte ^= ((row>>3)&7)<<4 on write AND read (row = m or d).
__global__ __launch_bounds__(256) void kv_k(const _Float16* __restrict__ Kp,
                                            const _Float16* __restrict__ Vhb,
                                            float* __restrict__ kvacc)
{
  __shared__ __align__(16) _Float16 sK[256 * 72];   // [m][l] stride 72, swizzled
  __shared__ __align__(16) _Float16 sV[64 * 72];    // [d][l]
  const int t = threadIdx.x, lane = t & 63, w = t >> 6;
  const int h = blockIdx.x;
  const int l0 = blockIdx.y * (L_ / KV_SPLIT);
  fx4 acc[4][4];
#pragma unroll
  for (int i = 0; i < 4; ++i)
#pragma unroll
    for (int j = 0; j < 4; ++j) acc[i][j] = (fx4){0.f, 0.f, 0.f, 0.f};
  const _Float16* Kbase = Kp + (long)h * L_ * 256;
  for (int kt = 0; kt < L_ / KV_SPLIT; kt += 64) {
    __syncthreads();
    // k' tile: 64 l x 256 m. 512 items (m8, l4), 2 per thread.
#pragma unroll
    for (int it = 0; it < 2; ++it) {
      int idx = t + it * 256;
      int m8 = idx & 31, bl = (idx >> 5) << 2;
      const _Float16* src = &Kbase[(long)(l0 + kt + bl) * 256 + m8 * 8];
      hx8 r0 = *(const hx8*)(src);
      hx8 r1 = *(const hx8*)(src + 256);
      hx8 r2 = *(const hx8*)(src + 512);
      hx8 r3 = *(const hx8*)(src + 768);
      int kx = (m8 & 7) << 4;
#pragma unroll
      for (int e = 0; e < 8; ++e) {
        hx4 v; v[0] = r0[e]; v[1] = r1[e]; v[2] = r2[e]; v[3] = r3[e];
        int byte = (((m8 * 8 + e) * 72 + bl) * 2) ^ kx;
        *(hx4*)((char*)sK + byte) = v;
      }
    }
    // v tile: 64 l x 64 d. 128 items, threads t<128.
    if (t < 128) {
      int d8 = t & 7, bl = (t >> 3) << 2;
      const _Float16* src = &Vhb[(long)(l0 + kt + bl) * 1024 + h * 64 + d8 * 8];
      hx8 r0 = *(const hx8*)(src);
      hx8 r1 = *(const hx8*)(src + 1024);
      hx8 r2 = *(const hx8*)(src + 2048);
      hx8 r3 = *(const hx8*)(src + 3072);
      int kx = d8 << 4;
#pragma unroll
      for (int e = 0; e < 8; ++e) {
        hx4 v; v[0] = r0[e]; v[1] = r1[e]; v[2] = r2[e]; v[3] = r3[e];
        int byte = (((d8 * 8 + e) * 72 + bl) * 2) ^ kx;
        *(hx4*)((char*)sV + byte) = v;
      }
    }
    __syncthreads();
#pragma unroll
    for (int kk = 0; kk < 64; kk += 32) {
      hx8 af[4], bf[4];
      int lfr = kk + ((lane >> 4) << 3);
#pragma unroll
      for (int i = 0; i < 4; ++i) {
        int r = i * 16 + (lane & 15);
        af[i] = *(const hx8*)((const char*)sV +
                ((((r * 72 + lfr) * 2)) ^ (((r >> 3) & 7) << 4)));
      }
#pragma unroll
      for (int j = 0; j < 4; ++j) {
        int r = w * 64 + j * 16 + (lane & 15);
        bf[j] = *(const hx8*)((const char*)sK +
                ((((r * 72 + lfr) * 2)) ^ (((r >> 3) & 7) << 4)));
      }
#pragma unroll
      for (int i = 0; i < 4; ++i)
#pragma unroll
        for (int j = 0; j < 4; ++j)
          acc[i][j] = __builtin_amdgcn_mfma_f32_16x16x32_f16(af[i], bf[j], acc[i][j], 0, 0, 0);
    }
  }
  float* obase = kvacc + (long)h * (64 * 256);
#pragma unroll
  for (int i = 0; i < 4; ++i)
#pragma unroll
    for (int j = 0; j < 4; ++j) {
      int d0 = i * 16 + ((lane >> 4) << 2);
      int m  = w * 64 + j * 16 + (lane & 15);
#pragma unroll
      for (int r = 0; r < 4; ++r)
        atomicAdd(&obase[(long)(d0 + r) * 256 + m], acc[i][j][r]);
    }
}

// ---------------------------------------------------------------------------
extern "C" void kernel_launch(void* const* d_in, const int* in_sizes, int n_in,
                              void* d_out, int out_size, void* d_ws, size_t ws_size,
                              hipStream_t stream) {
  const float* x     = (const float*)d_in[0];
  const float* pos   = (const float*)d_in[1];
  const float* slp   = (const float*)d_in[2];
  const float* Wv    = (const float*)d_in[3];
  const float* Wo    = (const float*)d_in[4];
  const float* Wpf   = (const float*)d_in[5];
  const float* scale = (const float*)d_in[6];
  const float* offs  = (const float*)d_in[7];
  const float* proj  = (const float*)d_in[8];
  float* out = (float*)d_out;
  char* ws = (char*)d_ws;

  // Arena ~218.7 MB. Aliases (stream-order-safe):
  //   ph2 = qpr, sh2 = kpr  (f16 [hi|lo] pos/slp; consumed by P|S before
  //   fourier overwrites qpr/kpr);  xh = Zb (consumed by V before z).
  // NOTE: Sb2 must follow Pb2 contiguously (+16777216 f16); kpr follows qpr.
  size_t o = 0;
  auto alloc = [&](size_t bytes) { char* p = ws + o; o += (bytes + 255) & ~(size_t)255; return p; };
  _Float16* Pb2    = (_Float16*)alloc(33554432);   // [2b][65536 lh][128 hi|lo] f16
  _Float16* Sb2    = (_Float16*)alloc(33554432);   //   == Pb2 + 16777216
  _Float16* qpr    = (_Float16*)alloc(33554432);   // per-b [H][L][256] f16
  _Float16* kpr    = (_Float16*)alloc(33554432);   //   == qpr + 16777216
  _Float16* Vh     = (_Float16*)alloc(33554432);   // [BL][1024] f16
  _Float16* Zb     = (_Float16*)alloc(33554432);   // [BL][1024] f16
  _Float16* WvT    = (_Float16*)alloc(2097152);
  _Float16* WoT    = (_Float16*)alloc(2097152);
  _Float16* Wpf3T  = (_Float16*)alloc(6291456);    // [1024][3072] [hi;hi;lo]
  _Float16* proj6T = (_Float16*)alloc(98304);      // [128][384] [hi|hi|lo|hi|hi|lo]
  float*    normsB = (float*)alloc(524288);        // [8192][16] f32 per super-batch
  float*    kvacc  = (float*)alloc(4194304);       // [BH][64][256] f32
  _Float16* kvh    = (_Float16*)alloc(2097152);
  _Float16* ph2 = qpr;                             // [8192][2048] f16 [hi|lo]
  _Float16* sh2 = kpr;
  _Float16* xh  = Zb;                              // [16384][1024] f16
  (void)Sb2; (void)ws_size; (void)in_sizes; (void)n_in; (void)out_size;

  // prep
  wt_k<<<dim3(16, 16), 256, 0, stream>>>(Wv, WvT);
  wt_k<<<dim3(16, 16), 256, 0, stream>>>(Wo, WoT);
  wpf3_k<<<dim3(16, 16), 256, 0, stream>>>(Wpf, Wpf3T);
  proj6_k<<<32, 256, 0, stream>>>(proj, proj6T);
  zero_k<<<256, 256, 0, stream>>>(kvacc, 262144);
  cvt16_k<<<8192, 256, 0, stream>>>(x, xh, 2097152);

  // V = xh @ W_v (pure f16, gload_lds staging), M=16384, grid (M,N)-swapped
  gemm_bt_k<128, 128, 0, 0, 0, _Float16><<<dim3(128, 8, 1), 256, 0, stream>>>(
      xh, WvT, Vh, 1024, 1024, 1024, 1024, 0, 0, 0, 0, 0, 0,
      nullptr, nullptr, nullptr, nullptr, nullptr);

  for (int sb = 0; sb < 2; ++sb) {
    const float* pos_sb = pos + (long)sb * 8192 * 1024;
    const float* slp_sb = slp + (long)sb * 8192 * 1024;
    // pre-split pos/slp to f16 [hi|lo]
    cvt_hilo_k<<<4096, 256, 0, stream>>>(pos_sb, ph2);
    cvt_hilo_k<<<4096, 256, 0, stream>>>(slp_sb, sh2);
    // Fused P|S: z=0 -> Pb2 = hilo(scale*(pos@W)); z=1 -> Sb2 =
    // hilo(offs*scale*(slp@W)) + slope norms. AMODE=4, virtual K=3072.
    gemm_bt_k<128, 128, 4, 10, 4, _Float16><<<dim3(64, 8, 2), 256, 0, stream>>>(
        ph2, Wpf3T, Pb2, 3072, 2048, 3072, 128, 0, 0, 0, 0, 0, 16777216L,
        nullptr, scale, offs, (const float*)sh2, normsB);

    for (int bb = 0; bb < 2; ++bb) {
      int b = sb * 2 + bb;
      _Float16* Vh_b  = Vh + (long)b * L_ * 1024;
      _Float16* Zb_b  = Zb + (long)b * L_ * 1024;
      float* kvacc_b  = kvacc + (long)b * H_ * 64 * 256;
      _Float16* kvh_b = kvh   + (long)b * H_ * 64 * 256;
      // fourier q (bz=0: K=192 {Ph,Pl,Ph}) + k (bz=1: K=384 adds S-sections
      // from Pb2+sAb) in one launch; pure f16 gload_lds vs proj6T.
      gemm_bt_k<128, 128, 5, 6, 1, _Float16><<<dim3(512, 1, 2), 256, 0, stream>>>(
          Pb2 + (long)bb * 8388608, proj6T, qpr, 384, 128, 384, 0,
          16777216L /*S-buffer offset*/, 0L, 0, 0, 0, 16777216L,
          normsB + (long)bb * 65536, nullptr, nullptr, nullptr, nullptr);
      // kv (split-K=16 over L with atomics) -> kvacc_b; cast to f16
      kv_k<<<dim3(16, KV_SPLIT), 256, 0, stream>>>(kpr, Vh_b, kvacc_b);
      cast_out_f16_k<<<1024, 256, 0, stream>>>(kvacc_b, kvh_b, 262144);
      // z = q'' @ kvT (batched over h), C -> Zb_b [L][1024]
      gemm_bt_k<128, 64, 0, 0, 0, _Float16><<<dim3(32, 1, 16), 256, 0, stream>>>(
          qpr, kvh_b, Zb_b, 256, 256, 256, 1024,
          0L, (long)L_ * 256, 0L, 16384L, 0L, 64L,
          nullptr, nullptr, nullptr, nullptr, nullptr);
    }
  }
  // out = z @ W_o (f32 out), M=16384
  gemm_bt_k<128, 128, 0, 0, 0, float><<<dim3(128, 8, 1), 256, 0, stream>>>(
      Zb, WoT, out, 1024, 1024, 1024, 1024, 0, 0, 0, 0, 0, 0,
      nullptr, nullptr, nullptr, nullptr, nullptr);
}